// Round 3
// baseline (122.781 us; speedup 1.0000x reference)
//
#include <hip/hip_runtime.h>

// Problem constants (fixed by setup_inputs): image (4,3,1024,1024) f32,
// pMtrx (4,2,3) f32, W=H=1024, align_corners=True.
//
// Forward-pass collapse: g0 = stop_gradient(grid) => grid - g0 == 0 exactly,
// so out = transpose(bilinear_sample(image, affine_grid(pMtrx,...)), (0,3,1,2)).
// The NUM_AUX noisy samples / 2x2 solves contribute exactly 0 to the output.
//
// R3: fix R2 compile error — __builtin_nontemporal_store needs a clang
// ext_vector_type, not HIP's float4 class. Same structure otherwise:
// 4 px/thread, 8B pair-loads per row-tap, float4 nontemporal stores.

#define B_  4
#define C_  3
#define HI  1024
#define WI  1024
#define HO  1024
#define WO  1024

typedef float vf4 __attribute__((ext_vector_type(4)));
struct __attribute__((packed)) fpair { float a, b; };  // 4-byte aligned 8B load

__global__ __launch_bounds__(256) void warp_bilinear4_kernel(
    const float* __restrict__ image,   // (B, C, HI, WI)
    const float* __restrict__ theta,   // (B, 2, 3)
    float* __restrict__ out)           // (B, C, HO, WO)
{
    // One block = one output row (256 threads x 4 px = 1024 = WO).
    const int h = blockIdx.x & (HO - 1);
    const int b = blockIdx.x >> 10;
    const int w0 = threadIdx.x << 2;

    const float* t = theta + b * 6;
    const float t0 = t[0], t1 = t[1], t2 = t[2];
    const float t3 = t[3], t4 = t[4], t5 = t[5];

    const float ys = -1.0f + 2.0f * (float)h / (float)(HO - 1);
    const float cy = t1 * ys + t2;   // x = t0*xs + cy
    const float dy = t4 * ys + t5;   // y = t3*xs + dy

    const float* imgb = image + (size_t)b * (C_ * HI * WI);
    float acc[C_][4];

#pragma unroll
    for (int px = 0; px < 4; ++px) {
        const int w = w0 + px;
        const float xs = -1.0f + 2.0f * (float)w / (float)(WO - 1);
        const float x = t0 * xs + cy;
        const float y = t3 * xs + dy;

        const float ix = (x + 1.0f) * 0.5f * (float)(WI - 1);
        const float iy = (y + 1.0f) * 0.5f * (float)(HI - 1);

        const float x0f = floorf(ix);
        const float y0f = floorf(iy);
        const float wx1 = ix - x0f;
        const float wy1 = iy - y0f;

        const int x0 = (int)x0f;
        const int y0 = (int)y0f;

        // validity-folded axis weights
        const float ax0 = (1.0f - wx1) * ((x0 >= 0 && x0 <= WI - 1) ? 1.0f : 0.0f);
        const float ax1 = wx1          * ((x0 >= -1 && x0 <= WI - 2) ? 1.0f : 0.0f);
        const float ay0 = (1.0f - wy1) * ((y0 >= 0 && y0 <= HI - 1) ? 1.0f : 0.0f);
        const float ay1 = wy1          * ((y0 >= -1 && y0 <= HI - 2) ? 1.0f : 0.0f);

        const int xb  = min(max(x0, 0), WI - 2);          // pair base, in-bounds
        const int xc0 = min(max(x0, 0), WI - 1);
        const int xc1 = min(max(x0 + 1, 0), WI - 1);
        const bool s0 = (xc0 != xb);   // x0-tap takes pair.b (only at right clamp)
        const bool s1 = (xc1 == xb);   // x1-tap takes pair.a (only at left clamp)

        const int yc0 = min(max(y0, 0), HI - 1);
        const int yc1 = min(max(y0 + 1, 0), HI - 1);
        const int o0 = yc0 * WI + xb;
        const int o1 = yc1 * WI + xb;

#pragma unroll
        for (int c = 0; c < C_; ++c) {
            const float* p = imgb + c * (HI * WI);
            const fpair p0 = *(const fpair*)(p + o0);
            const fpair p1 = *(const fpair*)(p + o1);
            const float va0 = s0 ? p0.b : p0.a;
            const float vb0 = s1 ? p0.a : p0.b;
            const float va1 = s0 ? p1.b : p1.a;
            const float vb1 = s1 ? p1.a : p1.b;
            acc[c][px] = ay0 * (ax0 * va0 + ax1 * vb0)
                       + ay1 * (ax0 * va1 + ax1 * vb1);
        }
    }

    float* ob = out + (size_t)b * (C_ * HO * WO) + h * WO + w0;
#pragma unroll
    for (int c = 0; c < C_; ++c) {
        vf4 v = { acc[c][0], acc[c][1], acc[c][2], acc[c][3] };
        __builtin_nontemporal_store(v, (vf4*)(ob + c * (HO * WO)));
    }
}

extern "C" void kernel_launch(void* const* d_in, const int* in_sizes, int n_in,
                              void* d_out, int out_size, void* d_ws, size_t ws_size,
                              hipStream_t stream) {
    const float* image = (const float*)d_in[0];
    const float* theta = (const float*)d_in[1];
    float* out = (float*)d_out;

    const int grid = B_ * HO;   // one block per output row = 4096 blocks
    warp_bilinear4_kernel<<<grid, 256, 0, stream>>>(image, theta, out);
}